// Round 8
// baseline (1366.923 us; speedup 1.0000x reference)
//
#include <hip/hip_runtime.h>

#define DIN 128
#define DH 128
#define DOUTC 64
#define NS 3
#define NL 3
#define EPSV 1e-5f

typedef __attribute__((ext_vector_type(8))) short bf16x8;
typedef __attribute__((ext_vector_type(4))) float f32x4;

static __device__ inline float bf2f(unsigned short h) {
    unsigned int u = ((unsigned int)h) << 16;
    return __builtin_bit_cast(float, u);
}
static __device__ inline unsigned short f2bf(float f) {
    unsigned int u = __builtin_bit_cast(unsigned int, f);
    u += 0x7fffu + ((u >> 16) & 1u);
    return (unsigned short)(u >> 16);
}
static __device__ inline float lo16(unsigned int u) {
    return __builtin_bit_cast(float, u << 16);
}
static __device__ inline float hi16(unsigned int u) {
    return __builtin_bit_cast(float, u & 0xffff0000u);
}
static __device__ inline unsigned int pkbf(float lo, float hi) {
    return ((unsigned int)f2bf(hi) << 16) | f2bf(lo);
}
static __device__ inline float sext8(unsigned int u, int k) {
    return (float)((int)(u << (24 - 8 * k)) >> 24);
}
static __device__ inline unsigned int pk8(float a, float b, float c, float d, float qs) {
    int q0 = (int)rintf(a * qs), q1 = (int)rintf(b * qs);
    int q2 = (int)rintf(c * qs), q3 = (int)rintf(d * qs);
    return (q0 & 255) | ((q1 & 255) << 8) | ((q2 & 255) << 16) | ((q3 & 255) << 24);
}

// ---------------- degree count, XCD-range-localized ----------------
__global__ __launch_bounds__(256) void k_count_r(const int* __restrict__ dst,
                                                 int* __restrict__ counts, int e, int n) {
    int rg = blockIdx.x & 7;
    int lo = rg * (n >> 3);
    int hi = (rg == 7) ? n : lo + (n >> 3);
    int nb = gridDim.x >> 3, bi = blockIdx.x >> 3;
    int e4 = e >> 2;
    const int4* dst4 = (const int4*)dst;
    for (int i = bi * 256 + threadIdx.x; i < e4; i += nb * 256) {
        int4 d = dst4[i];
        if (d.x >= lo && d.x < hi) atomicAdd(&counts[d.x], 1);
        if (d.y >= lo && d.y < hi) atomicAdd(&counts[d.y], 1);
        if (d.z >= lo && d.z < hi) atomicAdd(&counts[d.z], 1);
        if (d.w >= lo && d.w < hi) atomicAdd(&counts[d.w], 1);
    }
    if (bi == 0 && (int)threadIdx.x < (e & 3)) {
        int d = dst[e4 * 4 + threadIdx.x];
        if (d >= lo && d < hi) atomicAdd(&counts[d], 1);
    }
}

__global__ void k_dis(const int* __restrict__ counts, float* __restrict__ dis, int n) {
    int i = blockIdx.x * blockDim.x + threadIdx.x;
    if (i < n) dis[i] = rsqrtf((float)counts[i] + 1.0f);
}

// ---------------- exclusive scan (3-phase) ----------------
__global__ void k_scanA(const int* __restrict__ counts, int* __restrict__ row_start,
                        int* __restrict__ bsums, int n) {
    __shared__ int s[512];
    int t = threadIdx.x;
    int i = blockIdx.x * 512 + t;
    int v = (i < n) ? counts[i] : 0;
    s[t] = v;
    __syncthreads();
    for (int off = 1; off < 512; off <<= 1) {
        int x = s[t];
        if (t >= off) x += s[t - off];
        __syncthreads();
        s[t] = x;
        __syncthreads();
    }
    if (i < n) row_start[i] = s[t] - v;
    if (t == 511) bsums[blockIdx.x] = s[511];
}

__global__ void k_scanB(int* __restrict__ bsums, int nb) {
    __shared__ int s[256];
    int t = threadIdx.x;
    int v = (t < nb) ? bsums[t] : 0;
    s[t] = v;
    __syncthreads();
    for (int off = 1; off < 256; off <<= 1) {
        int x = s[t];
        if (t >= off) x += s[t - off];
        __syncthreads();
        s[t] = x;
        __syncthreads();
    }
    if (t < nb) bsums[t] = s[t] - v;
}

__global__ void k_scanC(int* __restrict__ row_start, const int* __restrict__ bsums, int n) {
    int i = blockIdx.x * blockDim.x + threadIdx.x;
    if (i < n) row_start[i] += bsums[i >> 9];
}

// ---------------- CSR fill ----------------
__global__ __launch_bounds__(256) void k_fill_r(const int* __restrict__ src,
                                                const int* __restrict__ dst,
                                                int* __restrict__ cursor,
                                                int* __restrict__ col, int e, int n) {
    int rg = blockIdx.x & 7;
    int lo = rg * (n >> 3);
    int hi = (rg == 7) ? n : lo + (n >> 3);
    int nb = gridDim.x >> 3, bi = blockIdx.x >> 3;
    int e4 = e >> 2;
    const int4* dst4 = (const int4*)dst;
    const int4* src4 = (const int4*)src;
    for (int i = bi * 256 + threadIdx.x; i < e4; i += nb * 256) {
        int4 d = dst4[i];
        int4 s = src4[i];
        if (d.x >= lo && d.x < hi) col[atomicAdd(&cursor[d.x], 1)] = s.x;
        if (d.y >= lo && d.y < hi) col[atomicAdd(&cursor[d.y], 1)] = s.y;
        if (d.z >= lo && d.z < hi) col[atomicAdd(&cursor[d.z], 1)] = s.z;
        if (d.w >= lo && d.w < hi) col[atomicAdd(&cursor[d.w], 1)] = s.w;
    }
    if (bi == 0 && (int)threadIdx.x < (e & 3)) {
        int d = dst[e4 * 4 + threadIdx.x];
        int s = src[e4 * 4 + threadIdx.x];
        if (d >= lo && d < hi) col[atomicAdd(&cursor[d], 1)] = s;
    }
}

// ---------------- weight prep ----------------
// Wt0: natural [s][o][i].  Wt1: within-scale permuted [s][o][lp],
//   lp = p*64 + r*4 + k  <->  lchan = (4p+k)*16 + r.
// Mcat: full permuted [o][pos], pos = s*128 + lp (same lp mapping).
__global__ void k_prep_w(const float* __restrict__ W0, const float* __restrict__ W1,
                         const float* __restrict__ W2, const float* __restrict__ Wf,
                         const float* __restrict__ b2, const float* __restrict__ bf,
                         unsigned short* __restrict__ Wt0hi, unsigned short* __restrict__ Wt0lo,
                         unsigned short* __restrict__ Wt1hi, unsigned short* __restrict__ Wt1lo,
                         unsigned short* __restrict__ Mhi, unsigned short* __restrict__ Mlo,
                         float* __restrict__ bcomb) {
    int idx = blockIdx.x * blockDim.x + threadIdx.x;
    if (idx < NS * DH * DH) {
        int s = idx / (DH * DH);
        int rem = idx % (DH * DH);
        int o = rem / DH, i = rem % DH;
        {
            float v = W0[(size_t)s * DH * DH + (size_t)i * DH + o];
            unsigned short h = f2bf(v);
            Wt0hi[idx] = h;
            Wt0lo[idx] = f2bf(v - bf2f(h));
        }
        {
            int lp = i;
            int p = lp >> 6, r = (lp >> 2) & 15, k = lp & 3;
            int lchan = (4 * p + k) * 16 + r;
            float v = W1[(size_t)s * DH * DH + (size_t)lchan * DH + o];
            unsigned short h = f2bf(v);
            Wt1hi[idx] = h;
            Wt1lo[idx] = f2bf(v - bf2f(h));
        }
    }
    if (idx < DOUTC * NS * DH) {   // [o][pos]
        int o = idx / (NS * DH);
        int pos = idx % (NS * DH);
        int s = pos >> 7, lp = pos & 127;
        int p = lp >> 6, r = (lp >> 2) & 15, k = lp & 3;
        int il = (4 * p + k) * 16 + r;
        float acc = 0.f;
        for (int c = 0; c < DOUTC; ++c)
            acc += W2[((size_t)s * DH + il) * DOUTC + c] * Wf[((size_t)s * DOUTC + c) * DOUTC + o];
        unsigned short h = f2bf(acc);
        Mhi[idx] = h;
        Mlo[idx] = f2bf(acc - bf2f(h));
    }
    if (idx < DOUTC) {
        float acc = bf[idx];
        for (int s = 0; s < NS; ++s)
            for (int c = 0; c < DOUTC; ++c)
                acc += b2[s * DOUTC + c] * Wf[((size_t)s * DOUTC + c) * DOUTC + idx];
        bcomb[idx] = acc;
    }
}

// ---------------- x fp32 -> int8 rows (scale absorbs dis) ----------------
__global__ __launch_bounds__(256) void k_cvtq(const float2* __restrict__ x,
                                              unsigned int* __restrict__ xq,
                                              float* __restrict__ xs,
                                              const float* __restrict__ dis, int n) {
    int wid = ((blockIdx.x * blockDim.x + threadIdx.x) >> 6);
    int lane = threadIdx.x & 63;
    if (wid >= n) return;
    float2 v = x[(size_t)wid * 64 + lane];
    float m = fmaxf(fabsf(v.x), fabsf(v.y));
    #pragma unroll
    for (int off = 32; off; off >>= 1) m = fmaxf(m, __shfl_xor(m, off));
    float qs = m > 0.f ? 127.f / m : 0.f;
    int q0 = (int)rintf(v.x * qs), q1 = (int)rintf(v.y * qs);
    ((unsigned short*)xq)[(size_t)wid * 64 + lane] =
        (unsigned short)((q0 & 255) | ((q1 & 255) << 8));
    if (lane == 0) xs[wid] = dis[wid] * m * (1.f / 127.f);
}

// ---------------- int8 CSR aggregation, 128ch -> z0 bf16 (natural) ----------------
__global__ __launch_bounds__(256) void k_agg128q(
        const unsigned int* __restrict__ xq, const float* __restrict__ xs,
        unsigned int* __restrict__ z0, const float* __restrict__ dis,
        const int* __restrict__ rowstart, const int* __restrict__ counts,
        const int* __restrict__ col, int n) {
    int wid = (blockIdx.x * blockDim.x + threadIdx.x) >> 6;
    int lane = threadIdx.x & 63;
    int half = lane >> 5, c = lane & 31;
    int nw = (gridDim.x * blockDim.x) >> 6;
    int ntask = (n + 1) >> 1;
    for (int w = wid; w < ntask; w += nw) {
        int v = w * 2 + half;
        int vc = v < n ? v : n - 1;
        float dv = dis[vc];
        const int* colp = col + rowstart[vc];
        int cnt = v < n ? counts[vc] : 0;
        unsigned int us = xq[(size_t)vc * 32 + c];
        float sv = xs[vc];
        float a0 = sv * sext8(us, 0), a1 = sv * sext8(us, 1);
        float a2 = sv * sext8(us, 2), a3 = sv * sext8(us, 3);
        int i = 0;
        for (; i + 8 <= cnt; i += 8) {
            #pragma unroll
            for (int k = 0; k < 8; ++k) {
                int s0 = colp[i + k];
                float sc = xs[s0];
                unsigned int u = xq[(size_t)s0 * 32 + c];
                a0 += sc * sext8(u, 0); a1 += sc * sext8(u, 1);
                a2 += sc * sext8(u, 2); a3 += sc * sext8(u, 3);
            }
        }
        for (; i < cnt; ++i) {
            int s0 = colp[i];
            float sc = xs[s0];
            unsigned int u = xq[(size_t)s0 * 32 + c];
            a0 += sc * sext8(u, 0); a1 += sc * sext8(u, 1);
            a2 += sc * sext8(u, 2); a3 += sc * sext8(u, 3);
        }
        if (v < n) {
            uint2 o = {pkbf(dv * a0, dv * a1), pkbf(dv * a2, dv * a3)};
            *(uint2*)&z0[(size_t)v * 64 + 2 * c] = o;
        }
    }
}

// ---------------- layer-0 GEMM + LN + fused int8 quant (per-scale row scales) ----------------
// h1q u32 j = (s*2+p)*16 + r16, byte k -> chan s*128 + (4p+k)*16 + r16.
__global__ __launch_bounds__(256, 4) void k_gemm0i(
        const unsigned short* __restrict__ A, const unsigned short* __restrict__ Whi,
        const unsigned short* __restrict__ Wlo, const float* __restrict__ bias,
        const float* __restrict__ gamma, const float* __restrict__ beta,
        const float* __restrict__ dis, unsigned int* __restrict__ h1q,
        float* __restrict__ hs4, int n) {
    int wave = threadIdx.x >> 6, lane = threadIdx.x & 63;
    int g = blockIdx.x * 4 + wave;
    if (g * 16 >= n) return;
    int r16 = lane & 15, g4 = lane >> 4;
    int row = g * 16 + r16;
    if (row >= n) row = n - 1;

    bf16x8 a[4];
    #pragma unroll
    for (int ks = 0; ks < 4; ++ks)
        a[ks] = *(const bf16x8*)&A[(size_t)row * DH + ks * 32 + g4 * 8];

    for (int s = 0; s < NS; ++s) {
        const unsigned short* whi = Whi + (size_t)s * DH * DH;
        const unsigned short* wlo = Wlo + (size_t)s * DH * DH;
        f32x4 acc[8];
        #pragma unroll
        for (int t = 0; t < 8; ++t) acc[t] = (f32x4){0.f, 0.f, 0.f, 0.f};
        #pragma unroll
        for (int ks = 0; ks < 4; ++ks) {
            #pragma unroll
            for (int t = 0; t < 8; ++t) {
                size_t wofs = (size_t)(t * 16 + r16) * DH + ks * 32 + g4 * 8;
                bf16x8 bh = *(const bf16x8*)&whi[wofs];
                bf16x8 bl = *(const bf16x8*)&wlo[wofs];
                acc[t] = __builtin_amdgcn_mfma_f32_16x16x32_bf16(a[ks], bh, acc[t], 0, 0, 0);
                acc[t] = __builtin_amdgcn_mfma_f32_16x16x32_bf16(a[ks], bl, acc[t], 0, 0, 0);
            }
        }
        float bia[8], gam[8], bet[8];
        #pragma unroll
        for (int t = 0; t < 8; ++t) {
            bia[t] = bias[s * DH + t * 16 + r16];
            gam[t] = gamma[(size_t)(s * NL + 0) * DH + t * 16 + r16];
            bet[t] = beta[(size_t)(s * NL + 0) * DH + t * 16 + r16];
        }
        #pragma unroll
        for (int r = 0; r < 4; ++r) {
            float y[8];
            float sm = 0.f, q = 0.f;
            #pragma unroll
            for (int t = 0; t < 8; ++t) {
                y[t] = fmaxf(acc[t][r] + bia[t], 0.f);
                sm += y[t];
                q += y[t] * y[t];
            }
            #pragma unroll
            for (int off = 8; off; off >>= 1) {
                sm += __shfl_xor(sm, off);
                q += __shfl_xor(q, off);
            }
            float mu = sm * (1.f / 128.f);
            float var = q * (1.f / 128.f) - mu * mu;
            float rstd = rsqrtf(var + EPSV);
            float o[8];
            float m = 0.f;
            #pragma unroll
            for (int t = 0; t < 8; ++t) {
                o[t] = (y[t] - mu) * rstd * gam[t] + bet[t];
                m = fmaxf(m, fabsf(o[t]));
            }
            #pragma unroll
            for (int off = 8; off; off >>= 1) m = fmaxf(m, __shfl_xor(m, off));
            float qs = m > 0.f ? 127.f / m : 0.f;
            int node = g * 16 + g4 * 4 + r;
            if (node < n) {
                unsigned int* pn = h1q + (size_t)node * 96;
                pn[(s * 2 + 0) * 16 + r16] = pk8(o[0], o[1], o[2], o[3], qs);
                pn[(s * 2 + 1) * 16 + r16] = pk8(o[4], o[5], o[6], o[7], qs);
                if (r16 == 0) hs4[(size_t)node * 4 + s] = dis[node] * m * (1.f / 127.f);
            }
        }
    }
}

// ---------------- int8 CSR aggregation, 384ch -> g1 bf16 in PERMUTED (pos) order ----------------
// lane c reads u32s {c, c+32, c+64} (one per scale); writes uint2 at
// po[((c>>4)&1)*32 + (c&15)*2 + s*64].
__global__ __launch_bounds__(256) void k_agg384qp(
        const unsigned int* __restrict__ hq, const float* __restrict__ hs4,
        unsigned int* __restrict__ g1, const float* __restrict__ dis,
        const int* __restrict__ rowstart, const int* __restrict__ counts,
        const int* __restrict__ col, int n) {
    int wid = (blockIdx.x * blockDim.x + threadIdx.x) >> 6;
    int lane = threadIdx.x & 63;
    int half = lane >> 5, c = lane & 31;
    int nw = (gridDim.x * blockDim.x) >> 6;
    int ntask = (n + 1) >> 1;
    for (int w = wid; w < ntask; w += nw) {
        int v = w * 2 + half;
        int vc = v < n ? v : n - 1;
        float dv = dis[vc];
        const int* colp = col + rowstart[vc];
        int cnt = v < n ? counts[vc] : 0;
        const unsigned int* rp = hq + (size_t)vc * 96;
        unsigned int u0 = rp[c], u1 = rp[c + 32], u2 = rp[c + 64];
        float4 sv = ((const float4*)hs4)[vc];
        float a[12];
        #pragma unroll
        for (int k = 0; k < 4; ++k) {
            a[k]     = sv.x * sext8(u0, k);
            a[4 + k] = sv.y * sext8(u1, k);
            a[8 + k] = sv.z * sext8(u2, k);
        }
        int i = 0;
        for (; i + 4 <= cnt; i += 4) {
            #pragma unroll
            for (int k4 = 0; k4 < 4; ++k4) {
                int s0 = colp[i + k4];
                float4 sc = ((const float4*)hs4)[s0];
                const unsigned int* p0 = hq + (size_t)s0 * 96;
                unsigned int w0 = p0[c], w1 = p0[c + 32], w2 = p0[c + 64];
                #pragma unroll
                for (int k = 0; k < 4; ++k) {
                    a[k]     += sc.x * sext8(w0, k);
                    a[4 + k] += sc.y * sext8(w1, k);
                    a[8 + k] += sc.z * sext8(w2, k);
                }
            }
        }
        for (; i < cnt; ++i) {
            int s0 = colp[i];
            float4 sc = ((const float4*)hs4)[s0];
            const unsigned int* p0 = hq + (size_t)s0 * 96;
            unsigned int w0 = p0[c], w1 = p0[c + 32], w2 = p0[c + 64];
            #pragma unroll
            for (int k = 0; k < 4; ++k) {
                a[k]     += sc.x * sext8(w0, k);
                a[4 + k] += sc.y * sext8(w1, k);
                a[8 + k] += sc.z * sext8(w2, k);
            }
        }
        if (v < n) {
            unsigned int* po = g1 + (size_t)v * 192;
            int b = ((c >> 4) & 1) * 32 + (c & 15) * 2;
            uint2 o0 = {pkbf(dv * a[0], dv * a[1]), pkbf(dv * a[2], dv * a[3])};
            *(uint2*)&po[b] = o0;
            uint2 o1 = {pkbf(dv * a[4], dv * a[5]), pkbf(dv * a[6], dv * a[7])};
            *(uint2*)&po[b + 64] = o1;
            uint2 o2 = {pkbf(dv * a[8], dv * a[9]), pkbf(dv * a[10], dv * a[11])};
            *(uint2*)&po[b + 128] = o2;
        }
    }
}

// ---------------- layer-1 GEMM (permuted A/W) + LN -> h2 bf16 in full pos order ----------------
__global__ __launch_bounds__(256, 4) void k_gemm1(
        const unsigned short* __restrict__ G, const unsigned short* __restrict__ Whi,
        const unsigned short* __restrict__ Wlo, const float* __restrict__ bias,
        const float* __restrict__ gamma, const float* __restrict__ beta,
        unsigned int* __restrict__ h2, int n) {
    int wave = threadIdx.x >> 6, lane = threadIdx.x & 63;
    int g = blockIdx.x * 4 + wave;
    if (g * 16 >= n) return;
    int r16 = lane & 15, g4 = lane >> 4;
    int row = g * 16 + r16;
    if (row >= n) row = n - 1;

    for (int s = 0; s < NS; ++s) {
        bf16x8 a[4];
        #pragma unroll
        for (int ks = 0; ks < 4; ++ks)
            a[ks] = *(const bf16x8*)&G[(size_t)row * (NS * DH) + s * DH + ks * 32 + g4 * 8];
        const unsigned short* whi = Whi + (size_t)s * DH * DH;
        const unsigned short* wlo = Wlo + (size_t)s * DH * DH;
        f32x4 acc[8];
        #pragma unroll
        for (int t = 0; t < 8; ++t) acc[t] = (f32x4){0.f, 0.f, 0.f, 0.f};
        #pragma unroll
        for (int ks = 0; ks < 4; ++ks) {
            #pragma unroll
            for (int t = 0; t < 8; ++t) {
                size_t wofs = (size_t)(t * 16 + r16) * DH + ks * 32 + g4 * 8;
                bf16x8 bh = *(const bf16x8*)&whi[wofs];
                bf16x8 bl = *(const bf16x8*)&wlo[wofs];
                acc[t] = __builtin_amdgcn_mfma_f32_16x16x32_bf16(a[ks], bh, acc[t], 0, 0, 0);
                acc[t] = __builtin_amdgcn_mfma_f32_16x16x32_bf16(a[ks], bl, acc[t], 0, 0, 0);
            }
        }
        float bia[8], gam[8], bet[8];
        #pragma unroll
        for (int t = 0; t < 8; ++t) {
            bia[t] = bias[s * DH + t * 16 + r16];
            gam[t] = gamma[(size_t)(s * NL + 1) * DH + t * 16 + r16];
            bet[t] = beta[(size_t)(s * NL + 1) * DH + t * 16 + r16];
        }
        #pragma unroll
        for (int r = 0; r < 4; ++r) {
            float y[8];
            float sm = 0.f, qq = 0.f;
            #pragma unroll
            for (int t = 0; t < 8; ++t) {
                y[t] = fmaxf(acc[t][r] + bia[t], 0.f);
                sm += y[t];
                qq += y[t] * y[t];
            }
            #pragma unroll
            for (int off = 8; off; off >>= 1) {
                sm += __shfl_xor(sm, off);
                qq += __shfl_xor(qq, off);
            }
            float mu = sm * (1.f / 128.f);
            float var = qq * (1.f / 128.f) - mu * mu;
            float rstd = rsqrtf(var + EPSV);
            float o[8];
            #pragma unroll
            for (int t = 0; t < 8; ++t)
                o[t] = (y[t] - mu) * rstd * gam[t] + bet[t];
            int node = g * 16 + g4 * 4 + r;
            if (node < n) {
                unsigned int* po = h2 + (size_t)node * 192;
                uint2 w0 = {pkbf(o[0], o[1]), pkbf(o[2], o[3])};
                *(uint2*)&po[s * 64 + r16 * 2] = w0;
                uint2 w1 = {pkbf(o[4], o[5]), pkbf(o[6], o[7])};
                *(uint2*)&po[s * 64 + 32 + r16 * 2] = w1;
            }
        }
    }
}

// ---------------- q-GEMM (pos-order A, permuted Mcat) + fused int8 quant ----------------
// qq u32 j = r16, byte k -> chan k*16 + r16.
__global__ __launch_bounds__(256, 4) void k_gemmq(
        const unsigned short* __restrict__ H, const unsigned short* __restrict__ Mhi,
        const unsigned short* __restrict__ Mlo, const float* __restrict__ dis,
        unsigned int* __restrict__ qq, float* __restrict__ qs2, int n) {
    int wave = threadIdx.x >> 6, lane = threadIdx.x & 63;
    int g = blockIdx.x * 4 + wave;
    if (g * 16 >= n) return;
    int r16 = lane & 15, g4 = lane >> 4;
    int row = g * 16 + r16;
    if (row >= n) row = n - 1;

    f32x4 qa[4];
    #pragma unroll
    for (int t = 0; t < 4; ++t) qa[t] = (f32x4){0.f, 0.f, 0.f, 0.f};
    #pragma unroll
    for (int ks = 0; ks < 12; ++ks) {
        bf16x8 av = *(const bf16x8*)&H[(size_t)row * (NS * DH) + ks * 32 + g4 * 8];
        #pragma unroll
        for (int t = 0; t < 4; ++t) {
            size_t wofs = (size_t)(t * 16 + r16) * (NS * DH) + ks * 32 + g4 * 8;
            bf16x8 bh = *(const bf16x8*)&Mhi[wofs];
            bf16x8 bl = *(const bf16x8*)&Mlo[wofs];
            qa[t] = __builtin_amdgcn_mfma_f32_16x16x32_bf16(av, bh, qa[t], 0, 0, 0);
            qa[t] = __builtin_amdgcn_mfma_f32_16x16x32_bf16(av, bl, qa[t], 0, 0, 0);
        }
    }
    #pragma unroll
    for (int r = 0; r < 4; ++r) {
        float v0 = qa[0][r], v1 = qa[1][r], v2 = qa[2][r], v3 = qa[3][r];
        float m = fmaxf(fmaxf(fabsf(v0), fabsf(v1)), fmaxf(fabsf(v2), fabsf(v3)));
        #pragma unroll
        for (int off = 8; off; off >>= 1) m = fmaxf(m, __shfl_xor(m, off));
        float qs = m > 0.f ? 127.f / m : 0.f;
        int node = g * 16 + g4 * 4 + r;
        if (node < n) {
            qq[(size_t)node * 16 + r16] = pk8(v0, v1, v2, v3, qs);
            if (r16 == 0) qs2[node] = dis[node] * m * (1.f / 127.f);
        }
    }
}

// ---------------- int8 CSR aggregation, 64ch -> out fp32 + bcomb ----------------
// u32 j = c, byte k -> chan k*16 + c.
__global__ __launch_bounds__(256) void k_agg64q(
        const unsigned int* __restrict__ qq, const float* __restrict__ qs2,
        float* __restrict__ out, const float* __restrict__ bcomb,
        const float* __restrict__ dis, const int* __restrict__ rowstart,
        const int* __restrict__ counts, const int* __restrict__ col, int n) {
    int wid = (blockIdx.x * blockDim.x + threadIdx.x) >> 6;
    int lane = threadIdx.x & 63;
    int g = lane >> 4, c = lane & 15;
    int nw = (gridDim.x * blockDim.x) >> 6;
    int ntask = (n + 3) >> 2;
    float bc0 = bcomb[c], bc1 = bcomb[16 + c], bc2 = bcomb[32 + c], bc3 = bcomb[48 + c];
    for (int w = wid; w < ntask; w += nw) {
        int v = w * 4 + g;
        int vc = v < n ? v : n - 1;
        float dv = dis[vc];
        const int* colp = col + rowstart[vc];
        int cnt = v < n ? counts[vc] : 0;
        unsigned int us = qq[(size_t)vc * 16 + c];
        float sv = qs2[vc];
        float a0 = sv * sext8(us, 0), a1 = sv * sext8(us, 1);
        float a2 = sv * sext8(us, 2), a3 = sv * sext8(us, 3);
        int i = 0;
        for (; i + 8 <= cnt; i += 8) {
            #pragma unroll
            for (int k = 0; k < 8; ++k) {
                int s0 = colp[i + k];
                float sc = qs2[s0];
                unsigned int u = qq[(size_t)s0 * 16 + c];
                a0 += sc * sext8(u, 0); a1 += sc * sext8(u, 1);
                a2 += sc * sext8(u, 2); a3 += sc * sext8(u, 3);
            }
        }
        for (; i < cnt; ++i) {
            int s0 = colp[i];
            float sc = qs2[s0];
            unsigned int u = qq[(size_t)s0 * 16 + c];
            a0 += sc * sext8(u, 0); a1 += sc * sext8(u, 1);
            a2 += sc * sext8(u, 2); a3 += sc * sext8(u, 3);
        }
        if (v < n) {
            float* po = out + (size_t)v * 64;
            po[c]      = dv * a0 + bc0;
            po[16 + c] = dv * a1 + bc1;
            po[32 + c] = dv * a2 + bc2;
            po[48 + c] = dv * a3 + bc3;
        }
    }
}

extern "C" void kernel_launch(void* const* d_in, const int* in_sizes, int n_in,
                              void* d_out, int out_size, void* d_ws, size_t ws_size,
                              hipStream_t stream) {
    const float* x    = (const float*)d_in[0];
    const int*   ei   = (const int*)d_in[1];
    const float* W0   = (const float*)d_in[2];
    const float* b0   = (const float*)d_in[3];
    const float* W1   = (const float*)d_in[4];
    const float* b1   = (const float*)d_in[5];
    const float* W2   = (const float*)d_in[6];
    const float* b2   = (const float*)d_in[7];
    const float* gamma= (const float*)d_in[8];
    const float* beta = (const float*)d_in[9];
    const float* Wf   = (const float*)d_in[10];
    const float* bf   = (const float*)d_in[11];
    float* out = (float*)d_out;

    const int n = in_sizes[0] / DIN;
    const int e = in_sizes[1] / 2;
    const int* src = ei;
    const int* dst = ei + e;

    char* ws = (char*)d_ws;
    auto alloc = [&](size_t bytes) {
        char* p = ws;
        ws += (bytes + 255) & ~(size_t)255;
        return p;
    };
    int*   counts   = (int*)alloc((size_t)n * 4);
    int*   cursor   = (int*)alloc((size_t)n * 4);
    int*   rowstart = (int*)alloc((size_t)n * 4);
    int*   bsums    = (int*)alloc(4096);
    float* dis      = (float*)alloc((size_t)n * 4);
    int*   col      = (int*)alloc((size_t)e * 4);
    unsigned short* Wt0hi = (unsigned short*)alloc((size_t)NS * DH * DH * 2);
    unsigned short* Wt0lo = (unsigned short*)alloc((size_t)NS * DH * DH * 2);
    unsigned short* Wt1hi = (unsigned short*)alloc((size_t)NS * DH * DH * 2);
    unsigned short* Wt1lo = (unsigned short*)alloc((size_t)NS * DH * DH * 2);
    unsigned short* Mhi   = (unsigned short*)alloc((size_t)DOUTC * NS * DH * 2);
    unsigned short* Mlo   = (unsigned short*)alloc((size_t)DOUTC * NS * DH * 2);
    float* bcomb    = (float*)alloc(DOUTC * 4);
    unsigned int* xq  = (unsigned int*)alloc((size_t)n * 32 * 4);
    float* xs         = (float*)alloc((size_t)n * 4);
    unsigned short* z0 = (unsigned short*)alloc((size_t)n * DH * 2);
    unsigned int* h1q = (unsigned int*)alloc((size_t)n * 96 * 4);
    float* hs4        = (float*)alloc((size_t)n * 16);
    unsigned short* g1cat = (unsigned short*)alloc((size_t)n * NS * DH * 2);
    unsigned int* h2  = (unsigned int*)alloc((size_t)n * 192 * 4);
    unsigned int* qq  = (unsigned int*)alloc((size_t)n * 16 * 4);
    float* qs2        = (float*)alloc((size_t)n * 4);

    hipMemsetAsync(counts, 0, (size_t)n * 4, stream);

    k_count_r<<<2048, 256, 0, stream>>>(dst, counts, e, n);
    k_dis<<<(n + 255) / 256, 256, 0, stream>>>(counts, dis, n);

    int nb = (n + 511) / 512;
    k_scanA<<<nb, 512, 0, stream>>>(counts, rowstart, bsums, n);
    k_scanB<<<1, 256, 0, stream>>>(bsums, nb);
    k_scanC<<<(n + 255) / 256, 256, 0, stream>>>(rowstart, bsums, n);
    hipMemcpyAsync(cursor, rowstart, (size_t)n * 4, hipMemcpyDeviceToDevice, stream);
    k_fill_r<<<2048, 256, 0, stream>>>(src, dst, cursor, col, e, n);

    k_prep_w<<<(NS * DH * DH + 255) / 256, 256, 0, stream>>>(
        W0, W1, W2, Wf, b2, bf, Wt0hi, Wt0lo, Wt1hi, Wt1lo, Mhi, Mlo, bcomb);
    k_cvtq<<<(n + 3) / 4, 256, 0, stream>>>((const float2*)x, xq, xs, dis, n);

    // z0 = P(x) via int8 gather
    k_agg128q<<<2048, 256, 0, stream>>>(xq, xs, (unsigned int*)z0,
                                        dis, rowstart, counts, col, n);
    const int GG = (n / 16 + 3) / 4;
    // h1q(int8) = quant(LN(relu(z0 @ W0_s + b0_s)))  [fused epilogue]
    k_gemm0i<<<GG, 256, 0, stream>>>(z0, Wt0hi, Wt0lo, b0, gamma, beta, dis, h1q, hs4, n);
    // g1cat(bf16, permuted) = P(h1)
    k_agg384qp<<<2048, 256, 0, stream>>>(h1q, hs4, (unsigned int*)g1cat,
                                         dis, rowstart, counts, col, n);
    // h2(bf16, pos-order) = LN(relu(g1 @ W1p_s + b1_s))
    k_gemm1<<<GG, 256, 0, stream>>>(g1cat, Wt1hi, Wt1lo, b1, gamma, beta, h2, n);
    // qq(int8) = quant(dis * (h2 @ Mcatp))  [fused epilogue]
    k_gemmq<<<GG, 256, 0, stream>>>((const unsigned short*)h2, Mhi, Mlo, dis, qq, qs2, n);
    // out = P(q) + bcomb
    k_agg64q<<<2048, 256, 0, stream>>>(qq, qs2, out, bcomb,
                                       dis, rowstart, counts, col, n);
}